// Round 24
// baseline (167.941 us; speedup 1.0000x reference)
//
#include <hip/hip_runtime.h>

#define N_NODES 50000
#define N_EDGES 800000
#define IN_C 128
#define HID_C 256
#define OUT_C 128
#define NBLK 196   // ceil(N_NODES / 256)
#define NPART 8    // dst partitions (= XCDs); width 6250
#define PART_W 6250
#define PCAP 110000  // partition capacity (mean 100K, 33 sigma margin)
#define KB 16        // blocks per partition in hist/scatter
#define EB 3125          // edge blocks
#define XCONV_BLKS 6250  // N_NODES*IN_C/4 / 256
#define WCONV_BLKS 64    // 16384 u32 / 256

typedef __attribute__((ext_vector_type(8))) short short8v;  // 8 bf16
typedef __attribute__((ext_vector_type(4))) float f32x4;

static __device__ __forceinline__ unsigned short f2bf(float f) {
  unsigned int u = __float_as_uint(f);
  unsigned int r = (u + 0x7fffu + ((u >> 16) & 1u)) >> 16;  // RNE
  return (unsigned short)r;
}
static __device__ __forceinline__ float bf2f(unsigned short h) {
  return __uint_as_float(((unsigned int)h) << 16);
}
// bf16 pair packing: u32 = bf(a) | bf(b)<<16  (natural k-order pairs)
static __device__ __forceinline__ unsigned int packBF2(float a, float b) {
  return (unsigned int)f2bf(a) | ((unsigned int)f2bf(b) << 16);
}

// ---------------------------------------------------------------------------
__global__ void zero8_k(int* __restrict__ pcount) {
  if (threadIdx.x < NPART) pcount[threadIdx.x] = 0;
}

// ---------------------------------------------------------------------------
// Partition pass + operand conversions (merged).
// Edge blocks [0,EB): detect int64/int32, bucket edges by dst/6250 into 8
// partition arrays. Per-block: LDS counts -> 8 global atomics -> LDS cursors.
// Edge record: u32 = local_d (13b) | src<<13. Blocks [EB,..): x/W -> bf16.
// ---------------------------------------------------------------------------
__global__ __launch_bounds__(256) void partition_conv_k(
    const int* __restrict__ ei, unsigned int* __restrict__ partbuf,
    int* __restrict__ pcount,
    const float* __restrict__ x, unsigned int* __restrict__ xbf,
    const float* __restrict__ W1, unsigned int* __restrict__ w1bf,
    const float* __restrict__ W2, unsigned int* __restrict__ w2bf) {
  const int b = blockIdx.x;
  if (b < EB) {
    __shared__ int s_is64;
    __shared__ int cnt[NPART], base[NPART], cur[NPART];
    if (threadIdx.x < NPART) {
      cnt[threadIdx.x] = 0;
      cur[threadIdx.x] = 0;
    }
    if (threadIdx.x == 0) {
      int nz = 0;
#pragma unroll
      for (int k = 0; k < 64; ++k) nz |= ei[2 * k + 1];
      s_is64 = (nz == 0) ? 1 : 0;
    }
    __syncthreads();
    const int is64 = s_is64;
    const int e = b * 256 + threadIdx.x;
    int s = 0, d = 0, p = 0;
    const bool valid = (e < N_EDGES);
    if (valid) {
      if (is64) {
        const uint2 sv = ((const uint2*)ei)[e];            // low word = src
        const uint2 dv = ((const uint2*)ei)[N_EDGES + e];  // low word = dst
        s = (int)sv.x;
        d = (int)dv.x;
      } else {
        s = ei[e];
        d = ei[N_EDGES + e];
      }
      p = d / PART_W;
      atomicAdd(&cnt[p], 1);  // LDS
    }
    __syncthreads();
    if (threadIdx.x < NPART)
      base[threadIdx.x] = atomicAdd(&pcount[threadIdx.x], cnt[threadIdx.x]);
    __syncthreads();
    if (valid) {
      const int o = atomicAdd(&cur[p], 1);  // LDS
      const int idx = base[p] + o;
      if (idx < PCAP) {
        partbuf[p * PCAP + idx] =
            (unsigned int)(d - p * PART_W) | ((unsigned int)s << 13);
      }
    }
  } else if (b < EB + XCONV_BLKS) {
    const int i = (b - EB) * 256 + threadIdx.x;  // over N*C/4 float4s
    const float4 f = *(const float4*)(x + (long)i * 4);
    uint2 u = {packBF2(f.x, f.y), packBF2(f.z, f.w)};
    *(uint2*)(xbf + (long)i * 2) = u;
  } else if (b < EB + XCONV_BLKS + WCONV_BLKS) {
    const int i = (b - EB - XCONV_BLKS) * 256 + threadIdx.x;  // u32 index
    const float2 f = *(const float2*)(W1 + (long)i * 2);
    w1bf[i] = packBF2(f.x, f.y);
  } else {
    const int i = (b - EB - XCONV_BLKS - WCONV_BLKS) * 256 + threadIdx.x;
    const float2 f = *(const float2*)(W2 + (long)i * 2);
    w2bf[i] = packBF2(f.x, f.y);
  }
}

// ---------------------------------------------------------------------------
// Per-chunk LDS histogram: block (p = bx&7, blk = bx>>3) counts its chunk of
// partition p into a 6250-bin LDS histogram, writes H[p][blk][bin].
// ---------------------------------------------------------------------------
__global__ __launch_bounds__(1024) void hist_k(const unsigned int* __restrict__ partbuf,
                                               const int* __restrict__ pcount,
                                               int* __restrict__ H) {
  const int p = blockIdx.x & 7;
  const int blk = blockIdx.x >> 3;
  __shared__ unsigned int hist[PART_W];
  for (int i = threadIdx.x; i < PART_W; i += 1024) hist[i] = 0;
  __syncthreads();
  const int np = pcount[p] < PCAP ? pcount[p] : PCAP;
  const int chunk = (np + KB - 1) / KB;
  const int s0 = blk * chunk;
  int s1 = s0 + chunk;
  if (s1 > np) s1 = np;
  const unsigned int* pb = partbuf + p * PCAP;
  for (int i = s0 + threadIdx.x; i < s1; i += 1024)
    atomicAdd(&hist[pb[i] & 0x1fffu], 1u);
  __syncthreads();
  int* Hrow = H + (p * KB + blk) * PART_W;
  for (int i = threadIdx.x; i < PART_W; i += 1024) Hrow[i] = (int)hist[i];
}

// ---------------------------------------------------------------------------
// Scans: per-node total degree from H (16 strided, coalesced-by-bin loads).
// ---------------------------------------------------------------------------
__global__ __launch_bounds__(256) void bsum_k(const int* __restrict__ H,
                                              int* __restrict__ bsum) {
  const int i = blockIdx.x * 256 + threadIdx.x;
  int v = 0;
  if (i < N_NODES) {
    const int p = i / PART_W, bin = i % PART_W;
    const int* Hp = H + p * KB * PART_W + bin;
#pragma unroll
    for (int blk = 0; blk < KB; ++blk) v += Hp[blk * PART_W];
  }
#pragma unroll
  for (int off = 32; off > 0; off >>= 1) v += __shfl_down(v, off, 64);
  __shared__ int ws[4];
  if ((threadIdx.x & 63) == 0) ws[threadIdx.x >> 6] = v;
  __syncthreads();
  if (threadIdx.x == 0) bsum[blockIdx.x] = ws[0] + ws[1] + ws[2] + ws[3];
}

__global__ __launch_bounds__(256) void bscan_k(const int* __restrict__ bsum,
                                               int* __restrict__ boff) {
  __shared__ int s[256];
  const int t = threadIdx.x;
  const int v = (t < NBLK) ? bsum[t] : 0;
  s[t] = v;
  __syncthreads();
  for (int off = 1; off < 256; off <<= 1) {
    const int tmp = (t >= off) ? s[t - off] : 0;
    __syncthreads();
    s[t] += tmp;
    __syncthreads();
  }
  if (t < NBLK) boff[t] = s[t] - v;
}

// bfinal: rowstart + dinv; convert H counts -> per-(blk,bin) base offsets.
__global__ __launch_bounds__(256) void bfinal_k(int* __restrict__ H,
                                                const int* __restrict__ boff,
                                                int* __restrict__ rowstart,
                                                float* __restrict__ dinv) {
  __shared__ int s[256];
  const int t = threadIdx.x;
  const int i = blockIdx.x * 256 + t;
  int dtot = 0;
  int p = 0, bin = 0;
  if (i < N_NODES) {
    p = i / PART_W;
    bin = i % PART_W;
    int* Hp = H + p * KB * PART_W + bin;
#pragma unroll
    for (int blk = 0; blk < KB; ++blk) dtot += Hp[blk * PART_W];
  }
  s[t] = dtot;
  __syncthreads();
  for (int off = 1; off < 256; off <<= 1) {
    const int tmp = (t >= off) ? s[t - off] : 0;
    __syncthreads();
    s[t] += tmp;
    __syncthreads();
  }
  const int run = boff[blockIdx.x] + s[t] - dtot;
  if (i < N_NODES) {
    rowstart[i] = run;
    dinv[i] = rsqrtf((float)dtot + 1.0f);
    int acc = run;
    int* Hp = H + p * KB * PART_W + bin;
#pragma unroll
    for (int blk = 0; blk < KB; ++blk) {
      const int c = Hp[blk * PART_W];
      Hp[blk * PART_W] = acc;
      acc += c;
    }
    if (i == N_NODES - 1) rowstart[N_NODES] = run + dtot;
  }
}

// ---------------------------------------------------------------------------
// Scatter: same chunking as hist_k; lrank from a fresh LDS histogram,
// pos = H_base[p][blk][bin] + lrank. p = bx&7 => per-XCD dst-ranges (bucket
// lines coalesce in that XCD's L2).
// ---------------------------------------------------------------------------
__global__ __launch_bounds__(1024) void scatter_k(const unsigned int* __restrict__ partbuf,
                                                  const int* __restrict__ pcount,
                                                  const int* __restrict__ H,
                                                  int* __restrict__ csr_src) {
  const int p = blockIdx.x & 7;
  const int blk = blockIdx.x >> 3;
  __shared__ unsigned int hist[PART_W];
  for (int i = threadIdx.x; i < PART_W; i += 1024) hist[i] = 0;
  __syncthreads();
  const int np = pcount[p] < PCAP ? pcount[p] : PCAP;
  const int chunk = (np + KB - 1) / KB;
  const int s0 = blk * chunk;
  int s1 = s0 + chunk;
  if (s1 > np) s1 = np;
  const unsigned int* pb = partbuf + p * PCAP;
  const int* Hrow = H + (p * KB + blk) * PART_W;
  for (int i = s0 + threadIdx.x; i < s1; i += 1024) {
    const unsigned int u = pb[i];
    const int ld = (int)(u & 0x1fffu);
    const int lr = (int)atomicAdd(&hist[ld], 1u);
    csr_src[Hrow[ld] + lr] = (int)(u >> 13);
  }
}

// ---------------------------------------------------------------------------
// FUSED both-layer GEMM, NT=64, W in plain bf16 (one MFMA per tile per ks):
//   GEMM1: h1 = relu(aggx @ W1^T + b1)   (K=128, M=256) -> LDS (bf16 packed)
//   GEMM2: h2 = h1 @ W2^T                (K=256, M=128) -> global bf16 packed
// aggx staged in LDS once; h1 never touches HBM.
// Swapped MFMA operand order (m89-verified): lane's 4 acc = 4 consecutive m
// for one n.
// ---------------------------------------------------------------------------
__global__ __launch_bounds__(256) void gemm_fused_k(
    const unsigned int* __restrict__ X,     // aggx bf16-packed [N][64]
    const unsigned int* __restrict__ W1BF,  // [256][64] bf16-pairs
    const float* __restrict__ b1,
    const unsigned int* __restrict__ W2BF,  // [128][128] bf16-pairs
    unsigned int* __restrict__ outBF) {     // h2 bf16-packed [N][64]
  constexpr int KP1 = 68;   // aggx LDS row stride (64 + 4 pad)
  constexpr int HP = 132;   // h1 LDS row stride (128 + 4 pad)
  __shared__ unsigned int xs[64 * KP1];   // 17.4 KB
  __shared__ unsigned int h1s[64 * HP];   // 33.8 KB

  const int tid = threadIdx.x;
  const int w = tid >> 6;
  const int l = tid & 63;
  const long nbase = (long)blockIdx.x * 64;
  const int kg = (l >> 4) * 8;
  const int lr = l & 15;
  const int mq0 = (l >> 4) * 4;

  // ---- Stage aggx tile: 64 rows x 64 u32 ----
#pragma unroll
  for (int i = 0; i < 4; ++i) {
    const int idx = (tid + i * 256) * 4;
    const int row = idx >> 6, col = idx & 63;
    long gr = nbase + row;
    if (gr > N_NODES - 1) gr = N_NODES - 1;  // clamp; final stores guarded
    const uint4 v = *(const uint4*)(X + gr * 64 + col);
    *(uint4*)(xs + row * KP1 + col) = v;
  }
  __syncthreads();

  // ---- GEMM1: wave w owns m in [w*64, w*64+64), K=128 ----
  {
    const int m0w = w * 64;
    f32x4 acc[4][4];
#pragma unroll
    for (int nt = 0; nt < 4; ++nt)
#pragma unroll
      for (int mt = 0; mt < 4; ++mt) acc[nt][mt] = {0.0f, 0.0f, 0.0f, 0.0f};

#pragma unroll
    for (int ks = 0; ks < 4; ++ks) {
      const int ko = ks * 32 + kg;  // bf16-element offset; /2 = u32 offset
      short8v wb[4];
#pragma unroll
      for (int mt = 0; mt < 4; ++mt)
        wb[mt] = *(const short8v*)(W1BF + (long)(m0w + mt * 16 + lr) * (IN_C / 2) +
                                   ko / 2);
#pragma unroll
      for (int nt = 0; nt < 4; ++nt) {
        const short8v xb = *(const short8v*)(xs + (nt * 16 + lr) * KP1 + ko / 2);
#pragma unroll
        for (int mt = 0; mt < 4; ++mt)
          acc[nt][mt] = __builtin_amdgcn_mfma_f32_16x16x32_bf16(wb[mt], xb,
                                                               acc[nt][mt], 0, 0, 0);
      }
    }

    // Epilogue 1: bias + relu -> packed bf16 into LDS h1s
#pragma unroll
    for (int nt = 0; nt < 4; ++nt) {
      const int nl = nt * 16 + lr;
#pragma unroll
      for (int mt = 0; mt < 4; ++mt) {
        const int mq = m0w + mt * 16 + mq0;
        const float4 bv = *(const float4*)(b1 + mq);
        const float v0 = fmaxf(acc[nt][mt][0] + bv.x, 0.0f);
        const float v1 = fmaxf(acc[nt][mt][1] + bv.y, 0.0f);
        const float v2 = fmaxf(acc[nt][mt][2] + bv.z, 0.0f);
        const float v3 = fmaxf(acc[nt][mt][3] + bv.w, 0.0f);
        uint2 o = {packBF2(v0, v1), packBF2(v2, v3)};
        *(uint2*)(h1s + nl * HP + mq / 2) = o;
      }
    }
  }
  __syncthreads();

  // ---- GEMM2: wave w owns m in [w*32, w*32+32), K=256 from LDS h1s ----
  {
    const int m0w = w * 32;
    f32x4 acc[4][2];
#pragma unroll
    for (int nt = 0; nt < 4; ++nt)
#pragma unroll
      for (int mt = 0; mt < 2; ++mt) acc[nt][mt] = {0.0f, 0.0f, 0.0f, 0.0f};

#pragma unroll
    for (int ks = 0; ks < 8; ++ks) {
      const int ko = ks * 32 + kg;
      short8v wb[2];
#pragma unroll
      for (int mt = 0; mt < 2; ++mt)
        wb[mt] = *(const short8v*)(W2BF + (long)(m0w + mt * 16 + lr) * (HID_C / 2) +
                                   ko / 2);
#pragma unroll
      for (int nt = 0; nt < 4; ++nt) {
        const short8v xb = *(const short8v*)(h1s + (nt * 16 + lr) * HP + ko / 2);
#pragma unroll
        for (int mt = 0; mt < 2; ++mt)
          acc[nt][mt] = __builtin_amdgcn_mfma_f32_16x16x32_bf16(wb[mt], xb,
                                                               acc[nt][mt], 0, 0, 0);
      }
    }

    // Epilogue 2: packed bf16 h2 to global
#pragma unroll
    for (int nt = 0; nt < 4; ++nt) {
      const long n = nbase + nt * 16 + lr;
      if (n < N_NODES) {
#pragma unroll
        for (int mt = 0; mt < 2; ++mt) {
          const int mq = m0w + mt * 16 + mq0;
          uint2 o = {packBF2(acc[nt][mt][0], acc[nt][mt][1]),
                     packBF2(acc[nt][mt][2], acc[nt][mt][3])};
          *(uint2*)(outBF + n * (OUT_C / 2) + mq / 2) = o;
        }
      }
    }
  }
}

// ---------------------------------------------------------------------------
// Gather-aggregate (one wave per destination node) over PACKED-BF16 rows.
// Lane reads 1 u32 = 2 channels per row. 8-edge unroll for MLP.
// OUT_BF: write packed bf16 u32 (feeds fused GEMM). Else fp32 (+bias) final.
// ---------------------------------------------------------------------------
template <int C, bool HAS_BIAS, bool OUT_BF>
__global__ __launch_bounds__(256) void gather_k(const int* __restrict__ rowstart,
                                                const int* __restrict__ csr_src,
                                                const float* __restrict__ dinv,
                                                const unsigned int* __restrict__ hbf,
                                                const float* __restrict__ bias,
                                                float* __restrict__ out,
                                                unsigned int* __restrict__ outBF) {
  const int v = (blockIdx.x * 256 + threadIdx.x) >> 6;
  if (v >= N_NODES) return;
  const int lane = threadIdx.x & 63;
  constexpr int CW = C / 2;  // u32 words per row
  const int rs = rowstart[v];
  const int re = rowstart[v + 1];
  const float dv = dinv[v];

  float a0 = 0.0f, a1 = 0.0f;

  int e = rs;
  for (; e + 7 < re; e += 8) {
    int s[8];
    float nn[8];
    unsigned int r[8];
#pragma unroll
    for (int j = 0; j < 8; ++j) s[j] = csr_src[e + j];
#pragma unroll
    for (int j = 0; j < 8; ++j) nn[j] = dv * dinv[s[j]];
#pragma unroll
    for (int j = 0; j < 8; ++j) r[j] = hbf[(long)s[j] * CW + lane];
#pragma unroll
    for (int j = 0; j < 8; ++j) {
      a0 += nn[j] * bf2f((unsigned short)r[j]);
      a1 += nn[j] * bf2f((unsigned short)(r[j] >> 16));
    }
  }
  for (; e + 3 < re; e += 4) {
    int s[4];
    float nn[4];
    unsigned int r[4];
#pragma unroll
    for (int j = 0; j < 4; ++j) s[j] = csr_src[e + j];
#pragma unroll
    for (int j = 0; j < 4; ++j) nn[j] = dv * dinv[s[j]];
#pragma unroll
    for (int j = 0; j < 4; ++j) r[j] = hbf[(long)s[j] * CW + lane];
#pragma unroll
    for (int j = 0; j < 4; ++j) {
      a0 += nn[j] * bf2f((unsigned short)r[j]);
      a1 += nn[j] * bf2f((unsigned short)(r[j] >> 16));
    }
  }
  for (; e < re; ++e) {
    const int s0 = csr_src[e];
    const float n0 = dv * dinv[s0];
    const unsigned int r0 = hbf[(long)s0 * CW + lane];
    a0 += n0 * bf2f((unsigned short)r0);
    a1 += n0 * bf2f((unsigned short)(r0 >> 16));
  }

  const float s2 = dv * dv;
  const unsigned int hv = hbf[(long)v * CW + lane];
  float o0 = s2 * bf2f((unsigned short)hv) + a0;
  float o1 = s2 * bf2f((unsigned short)(hv >> 16)) + a1;
  if (HAS_BIAS) {
    const float2 bv = *(const float2*)(bias + lane * 2);
    o0 += bv.x;
    o1 += bv.y;
  }
  if (OUT_BF) {
    outBF[(long)v * CW + lane] = packBF2(o0, o1);
  } else {
    const float2 o = {o0, o1};
    *(float2*)(out + (long)v * CW * 2 + lane * 2) = o;
  }
}

// ---------------------------------------------------------------------------
extern "C" void kernel_launch(void* const* d_in, const int* in_sizes, int n_in,
                              void* d_out, int out_size, void* d_ws, size_t ws_size,
                              hipStream_t stream) {
  (void)in_sizes; (void)n_in; (void)out_size; (void)ws_size;

  const float* x  = (const float*)d_in[0];
  const int*   ei = (const int*)d_in[1];
  const float* W1 = (const float*)d_in[2];
  const float* b1 = (const float*)d_in[3];
  const float* W2 = (const float*)d_in[4];
  const float* b2 = (const float*)d_in[5];
  float* out = (float*)d_out;

  // Workspace layout (bytes):
  char* ws = (char*)d_ws;
  unsigned int* partbuf = (unsigned int*)(ws + 0);        //  3.52 MB (8 x PCAP u32)
  int*   csr_src  = (int*)(ws + 3600000);      //  3.2 MB
  int*   H        = (int*)(ws + 6800000);      //  3.2 MB (8 x 16 x 6250)
  int*   pcount   = (int*)(ws + 10000000);     //  32 B
  int*   rowstart = (int*)(ws + 10000128);     //  0.2 MB (N+1)
  float* dinv     = (float*)(ws + 10200640);   //  0.2 MB
  int*   bsum     = (int*)(ws + 10400640);
  int*   boff     = (int*)(ws + 10401664);
  unsigned int* w1bf   = (unsigned int*)(ws + 10500000);  // 65.5 KB
  unsigned int* w2bf   = (unsigned int*)(ws + 10600000);  // 65.5 KB
  unsigned int* aggxbf = (unsigned int*)(ws + 11000000);  // 12.8 MB (bf16 packed)
  unsigned int* h2bf   = (unsigned int*)(ws + 24000000);  // 12.8 MB (bf16 packed)
  unsigned int* xbf    = (unsigned int*)(ws + 91200000);  // 12.8 MB

  const int GB = (N_NODES + 3) / 4;  // gather: 1 node/wave

  // ---- Preproc: atomic-free CSR via two-level LDS counting sort ----
  zero8_k<<<1, 64, 0, stream>>>(pcount);
  partition_conv_k<<<EB + XCONV_BLKS + 2 * WCONV_BLKS, 256, 0, stream>>>(
      ei, partbuf, pcount, x, xbf, W1, w1bf, W2, w2bf);
  hist_k<<<NPART * KB, 1024, 0, stream>>>(partbuf, pcount, H);
  bsum_k<<<NBLK, 256, 0, stream>>>(H, bsum);
  bscan_k<<<1, 256, 0, stream>>>(bsum, boff);
  bfinal_k<<<NBLK, 256, 0, stream>>>(H, boff, rowstart, dinv);
  scatter_k<<<NPART * KB, 1024, 0, stream>>>(partbuf, pcount, H, csr_src);

  // ---- Layer 1 gather: aggx = agg(x_bf16) (bf16 out) ----
  gather_k<IN_C, false, true><<<GB, 256, 0, stream>>>(
      rowstart, csr_src, dinv, xbf, nullptr, nullptr, aggxbf);

  // ---- Fused GEMM1+GEMM2: h2 = relu(aggx@W1^T + b1) @ W2^T (h1 stays in LDS)
  gemm_fused_k<<<(N_NODES + 63) / 64, 256, 0, stream>>>(aggxbf, w1bf, b1, w2bf,
                                                        h2bf);

  // ---- Layer 2 gather: out = agg(h2_bf16) + b2 ----
  gather_k<OUT_C, true, false><<<GB, 256, 0, stream>>>(
      rowstart, csr_src, dinv, h2bf, b2, out, nullptr);
}

// Round 25
// 153.138 us; speedup vs baseline: 1.0967x; 1.0967x over previous
//
#include <hip/hip_runtime.h>

#define N_NODES 50000
#define N_EDGES 800000
#define IN_C 128
#define HID_C 256
#define OUT_C 128
#define NBLK 196   // ceil(N_NODES / 256)
#define NPART 8    // dst partitions (= XCDs); width 6250
#define PART_W 6250
#define KB2 32     // chunks per partition pass
#define CHUNK (N_EDGES / KB2)  // 25000 edges
#define EB 3125          // edge blocks
#define XCONV_BLKS 6250  // N_NODES*IN_C/4 / 256
#define WCONV_BLKS 64    // 16384 u32 / 256

typedef __attribute__((ext_vector_type(8))) short short8v;  // 8 bf16
typedef __attribute__((ext_vector_type(4))) float f32x4;

static __device__ __forceinline__ unsigned short f2bf(float f) {
  unsigned int u = __float_as_uint(f);
  unsigned int r = (u + 0x7fffu + ((u >> 16) & 1u)) >> 16;  // RNE
  return (unsigned short)r;
}
static __device__ __forceinline__ float bf2f(unsigned short h) {
  return __uint_as_float(((unsigned int)h) << 16);
}
// bf16 pair packing: u32 = bf(a) | bf(b)<<16  (natural k-order pairs)
static __device__ __forceinline__ unsigned int packBF2(float a, float b) {
  return (unsigned int)f2bf(a) | ((unsigned int)f2bf(b) << 16);
}

// ---------------------------------------------------------------------------
// Streaming edge conversion (NO atomics) + operand conversions (merged).
// edata[e] = d | s<<16 (both < 65536). Blocks [EB,..): x/W -> bf16.
// ---------------------------------------------------------------------------
__global__ __launch_bounds__(256) void convert_conv_k(
    const int* __restrict__ ei, unsigned int* __restrict__ edata,
    const float* __restrict__ x, unsigned int* __restrict__ xbf,
    const float* __restrict__ W1, unsigned int* __restrict__ w1bf,
    const float* __restrict__ W2, unsigned int* __restrict__ w2bf) {
  const int b = blockIdx.x;
  if (b < EB) {
    __shared__ int s_is64;
    if (threadIdx.x == 0) {
      int nz = 0;
#pragma unroll
      for (int k = 0; k < 64; ++k) nz |= ei[2 * k + 1];
      s_is64 = (nz == 0) ? 1 : 0;
    }
    __syncthreads();
    const int is64 = s_is64;
    const int e = b * 256 + threadIdx.x;
    if (e < N_EDGES) {
      int s, d;
      if (is64) {
        const uint2 sv = ((const uint2*)ei)[e];            // low word = src
        const uint2 dv = ((const uint2*)ei)[N_EDGES + e];  // low word = dst
        s = (int)sv.x;
        d = (int)dv.x;
      } else {
        s = ei[e];
        d = ei[N_EDGES + e];
      }
      edata[e] = (unsigned int)d | ((unsigned int)s << 16);
    }
  } else if (b < EB + XCONV_BLKS) {
    const int i = (b - EB) * 256 + threadIdx.x;  // over N*C/4 float4s
    const float4 f = *(const float4*)(x + (long)i * 4);
    uint2 u = {packBF2(f.x, f.y), packBF2(f.z, f.w)};
    *(uint2*)(xbf + (long)i * 2) = u;
  } else if (b < EB + XCONV_BLKS + WCONV_BLKS) {
    const int i = (b - EB - XCONV_BLKS) * 256 + threadIdx.x;  // u32 index
    const float2 f = *(const float2*)(W1 + (long)i * 2);
    w1bf[i] = packBF2(f.x, f.y);
  } else {
    const int i = (b - EB - XCONV_BLKS - WCONV_BLKS) * 256 + threadIdx.x;
    const float2 f = *(const float2*)(W2 + (long)i * 2);
    w2bf[i] = packBF2(f.x, f.y);
  }
}

// ---------------------------------------------------------------------------
// Per-(partition,chunk) LDS histogram: block (p=bx&7, c=bx>>3) reads chunk c
// of the FULL edge list, filters dst-partition p, counts local_d into LDS,
// writes H[p][c][bin]. 256 blocks, no global atomics anywhere.
// ---------------------------------------------------------------------------
__global__ __launch_bounds__(1024) void hist_k(const unsigned int* __restrict__ edata,
                                               int* __restrict__ H) {
  const int p = blockIdx.x & 7;
  const int c = blockIdx.x >> 3;
  __shared__ unsigned int hist[PART_W];
  for (int i = threadIdx.x; i < PART_W; i += 1024) hist[i] = 0;
  __syncthreads();
  const int s0 = c * CHUNK;
  for (int i = s0 + threadIdx.x; i < s0 + CHUNK; i += 1024) {
    const unsigned int u = edata[i];
    const int d = (int)(u & 0xffffu);
    if (d / PART_W == p) atomicAdd(&hist[d - p * PART_W], 1u);
  }
  __syncthreads();
  int* Hrow = H + (p * KB2 + c) * PART_W;
  for (int i = threadIdx.x; i < PART_W; i += 1024) Hrow[i] = (int)hist[i];
}

// ---------------------------------------------------------------------------
// Scans: per-node total degree from H.
// ---------------------------------------------------------------------------
__global__ __launch_bounds__(256) void bsum_k(const int* __restrict__ H,
                                              int* __restrict__ bsum) {
  const int i = blockIdx.x * 256 + threadIdx.x;
  int v = 0;
  if (i < N_NODES) {
    const int p = i / PART_W, bin = i % PART_W;
    const int* Hp = H + p * KB2 * PART_W + bin;
#pragma unroll
    for (int c = 0; c < KB2; ++c) v += Hp[c * PART_W];
  }
#pragma unroll
  for (int off = 32; off > 0; off >>= 1) v += __shfl_down(v, off, 64);
  __shared__ int ws[4];
  if ((threadIdx.x & 63) == 0) ws[threadIdx.x >> 6] = v;
  __syncthreads();
  if (threadIdx.x == 0) bsum[blockIdx.x] = ws[0] + ws[1] + ws[2] + ws[3];
}

__global__ __launch_bounds__(256) void bscan_k(const int* __restrict__ bsum,
                                               int* __restrict__ boff) {
  __shared__ int s[256];
  const int t = threadIdx.x;
  const int v = (t < NBLK) ? bsum[t] : 0;
  s[t] = v;
  __syncthreads();
  for (int off = 1; off < 256; off <<= 1) {
    const int tmp = (t >= off) ? s[t - off] : 0;
    __syncthreads();
    s[t] += tmp;
    __syncthreads();
  }
  if (t < NBLK) boff[t] = s[t] - v;
}

// bfinal: rowstart + dinv; convert H counts -> per-(chunk,bin) base offsets.
__global__ __launch_bounds__(256) void bfinal_k(int* __restrict__ H,
                                                const int* __restrict__ boff,
                                                int* __restrict__ rowstart,
                                                float* __restrict__ dinv) {
  __shared__ int s[256];
  const int t = threadIdx.x;
  const int i = blockIdx.x * 256 + t;
  int dtot = 0;
  int p = 0, bin = 0;
  if (i < N_NODES) {
    p = i / PART_W;
    bin = i % PART_W;
    int* Hp = H + p * KB2 * PART_W + bin;
#pragma unroll
    for (int c = 0; c < KB2; ++c) dtot += Hp[c * PART_W];
  }
  s[t] = dtot;
  __syncthreads();
  for (int off = 1; off < 256; off <<= 1) {
    const int tmp = (t >= off) ? s[t - off] : 0;
    __syncthreads();
    s[t] += tmp;
    __syncthreads();
  }
  const int run = boff[blockIdx.x] + s[t] - dtot;
  if (i < N_NODES) {
    rowstart[i] = run;
    dinv[i] = rsqrtf((float)dtot + 1.0f);
    int acc = run;
    int* Hp = H + p * KB2 * PART_W + bin;
#pragma unroll
    for (int c = 0; c < KB2; ++c) {
      const int cnt = Hp[c * PART_W];
      Hp[c * PART_W] = acc;
      acc += cnt;
    }
    if (i == N_NODES - 1) rowstart[N_NODES] = run + dtot;
  }
}

// ---------------------------------------------------------------------------
// Scatter: same (p,c) decomposition; lrank via LDS histogram,
// pos = H_base[p][c][bin] + lrank. p = bx&7 => per-XCD dst-ranges.
// ---------------------------------------------------------------------------
__global__ __launch_bounds__(1024) void scatter_k(const unsigned int* __restrict__ edata,
                                                  const int* __restrict__ H,
                                                  int* __restrict__ csr_src) {
  const int p = blockIdx.x & 7;
  const int c = blockIdx.x >> 3;
  __shared__ unsigned int hist[PART_W];
  for (int i = threadIdx.x; i < PART_W; i += 1024) hist[i] = 0;
  __syncthreads();
  const int s0 = c * CHUNK;
  const int* Hrow = H + (p * KB2 + c) * PART_W;
  for (int i = s0 + threadIdx.x; i < s0 + CHUNK; i += 1024) {
    const unsigned int u = edata[i];
    const int d = (int)(u & 0xffffu);
    if (d / PART_W == p) {
      const int ld = d - p * PART_W;
      const int lr = (int)atomicAdd(&hist[ld], 1u);
      csr_src[Hrow[ld] + lr] = (int)(u >> 16);
    }
  }
}

// ---------------------------------------------------------------------------
// FUSED both-layer GEMM, NT=64, W in plain bf16 (one MFMA per tile per ks):
//   GEMM1: h1 = relu(aggx @ W1^T + b1)   (K=128, M=256) -> LDS (bf16 packed)
//   GEMM2: h2 = h1 @ W2^T                (K=256, M=128) -> global bf16 packed
// aggx staged in LDS once; h1 never touches HBM.
// Swapped MFMA operand order (m89-verified): lane's 4 acc = 4 consecutive m
// for one n.
// ---------------------------------------------------------------------------
__global__ __launch_bounds__(256) void gemm_fused_k(
    const unsigned int* __restrict__ X,     // aggx bf16-packed [N][64]
    const unsigned int* __restrict__ W1BF,  // [256][64] bf16-pairs
    const float* __restrict__ b1,
    const unsigned int* __restrict__ W2BF,  // [128][128] bf16-pairs
    unsigned int* __restrict__ outBF) {     // h2 bf16-packed [N][64]
  constexpr int KP1 = 68;   // aggx LDS row stride (64 + 4 pad)
  constexpr int HP = 132;   // h1 LDS row stride (128 + 4 pad)
  __shared__ unsigned int xs[64 * KP1];   // 17.4 KB
  __shared__ unsigned int h1s[64 * HP];   // 33.8 KB

  const int tid = threadIdx.x;
  const int w = tid >> 6;
  const int l = tid & 63;
  const long nbase = (long)blockIdx.x * 64;
  const int kg = (l >> 4) * 8;
  const int lr = l & 15;
  const int mq0 = (l >> 4) * 4;

  // ---- Stage aggx tile: 64 rows x 64 u32 ----
#pragma unroll
  for (int i = 0; i < 4; ++i) {
    const int idx = (tid + i * 256) * 4;
    const int row = idx >> 6, col = idx & 63;
    long gr = nbase + row;
    if (gr > N_NODES - 1) gr = N_NODES - 1;  // clamp; final stores guarded
    const uint4 v = *(const uint4*)(X + gr * 64 + col);
    *(uint4*)(xs + row * KP1 + col) = v;
  }
  __syncthreads();

  // ---- GEMM1: wave w owns m in [w*64, w*64+64), K=128 ----
  {
    const int m0w = w * 64;
    f32x4 acc[4][4];
#pragma unroll
    for (int nt = 0; nt < 4; ++nt)
#pragma unroll
      for (int mt = 0; mt < 4; ++mt) acc[nt][mt] = {0.0f, 0.0f, 0.0f, 0.0f};

#pragma unroll
    for (int ks = 0; ks < 4; ++ks) {
      const int ko = ks * 32 + kg;  // bf16-element offset; /2 = u32 offset
      short8v wb[4];
#pragma unroll
      for (int mt = 0; mt < 4; ++mt)
        wb[mt] = *(const short8v*)(W1BF + (long)(m0w + mt * 16 + lr) * (IN_C / 2) +
                                   ko / 2);
#pragma unroll
      for (int nt = 0; nt < 4; ++nt) {
        const short8v xb = *(const short8v*)(xs + (nt * 16 + lr) * KP1 + ko / 2);
#pragma unroll
        for (int mt = 0; mt < 4; ++mt)
          acc[nt][mt] = __builtin_amdgcn_mfma_f32_16x16x32_bf16(wb[mt], xb,
                                                               acc[nt][mt], 0, 0, 0);
      }
    }

    // Epilogue 1: bias + relu -> packed bf16 into LDS h1s
#pragma unroll
    for (int nt = 0; nt < 4; ++nt) {
      const int nl = nt * 16 + lr;
#pragma unroll
      for (int mt = 0; mt < 4; ++mt) {
        const int mq = m0w + mt * 16 + mq0;
        const float4 bv = *(const float4*)(b1 + mq);
        const float v0 = fmaxf(acc[nt][mt][0] + bv.x, 0.0f);
        const float v1 = fmaxf(acc[nt][mt][1] + bv.y, 0.0f);
        const float v2 = fmaxf(acc[nt][mt][2] + bv.z, 0.0f);
        const float v3 = fmaxf(acc[nt][mt][3] + bv.w, 0.0f);
        uint2 o = {packBF2(v0, v1), packBF2(v2, v3)};
        *(uint2*)(h1s + nl * HP + mq / 2) = o;
      }
    }
  }
  __syncthreads();

  // ---- GEMM2: wave w owns m in [w*32, w*32+32), K=256 from LDS h1s ----
  {
    const int m0w = w * 32;
    f32x4 acc[4][2];
#pragma unroll
    for (int nt = 0; nt < 4; ++nt)
#pragma unroll
      for (int mt = 0; mt < 2; ++mt) acc[nt][mt] = {0.0f, 0.0f, 0.0f, 0.0f};

#pragma unroll
    for (int ks = 0; ks < 8; ++ks) {
      const int ko = ks * 32 + kg;
      short8v wb[2];
#pragma unroll
      for (int mt = 0; mt < 2; ++mt)
        wb[mt] = *(const short8v*)(W2BF + (long)(m0w + mt * 16 + lr) * (HID_C / 2) +
                                   ko / 2);
#pragma unroll
      for (int nt = 0; nt < 4; ++nt) {
        const short8v xb = *(const short8v*)(h1s + (nt * 16 + lr) * HP + ko / 2);
#pragma unroll
        for (int mt = 0; mt < 2; ++mt)
          acc[nt][mt] = __builtin_amdgcn_mfma_f32_16x16x32_bf16(wb[mt], xb,
                                                               acc[nt][mt], 0, 0, 0);
      }
    }

    // Epilogue 2: packed bf16 h2 to global
#pragma unroll
    for (int nt = 0; nt < 4; ++nt) {
      const long n = nbase + nt * 16 + lr;
      if (n < N_NODES) {
#pragma unroll
        for (int mt = 0; mt < 2; ++mt) {
          const int mq = m0w + mt * 16 + mq0;
          uint2 o = {packBF2(acc[nt][mt][0], acc[nt][mt][1]),
                     packBF2(acc[nt][mt][2], acc[nt][mt][3])};
          *(uint2*)(outBF + n * (OUT_C / 2) + mq / 2) = o;
        }
      }
    }
  }
}

// ---------------------------------------------------------------------------
// Gather-aggregate (one wave per destination node) over PACKED-BF16 rows.
// Lane reads 1 u32 = 2 channels per row. 8-edge unroll for MLP.
// OUT_BF: write packed bf16 u32 (feeds fused GEMM). Else fp32 (+bias) final.
// ---------------------------------------------------------------------------
template <int C, bool HAS_BIAS, bool OUT_BF>
__global__ __launch_bounds__(256) void gather_k(const int* __restrict__ rowstart,
                                                const int* __restrict__ csr_src,
                                                const float* __restrict__ dinv,
                                                const unsigned int* __restrict__ hbf,
                                                const float* __restrict__ bias,
                                                float* __restrict__ out,
                                                unsigned int* __restrict__ outBF) {
  const int v = (blockIdx.x * 256 + threadIdx.x) >> 6;
  if (v >= N_NODES) return;
  const int lane = threadIdx.x & 63;
  constexpr int CW = C / 2;  // u32 words per row
  const int rs = rowstart[v];
  const int re = rowstart[v + 1];
  const float dv = dinv[v];

  float a0 = 0.0f, a1 = 0.0f;

  int e = rs;
  for (; e + 7 < re; e += 8) {
    int s[8];
    float nn[8];
    unsigned int r[8];
#pragma unroll
    for (int j = 0; j < 8; ++j) s[j] = csr_src[e + j];
#pragma unroll
    for (int j = 0; j < 8; ++j) nn[j] = dv * dinv[s[j]];
#pragma unroll
    for (int j = 0; j < 8; ++j) r[j] = hbf[(long)s[j] * CW + lane];
#pragma unroll
    for (int j = 0; j < 8; ++j) {
      a0 += nn[j] * bf2f((unsigned short)r[j]);
      a1 += nn[j] * bf2f((unsigned short)(r[j] >> 16));
    }
  }
  for (; e + 3 < re; e += 4) {
    int s[4];
    float nn[4];
    unsigned int r[4];
#pragma unroll
    for (int j = 0; j < 4; ++j) s[j] = csr_src[e + j];
#pragma unroll
    for (int j = 0; j < 4; ++j) nn[j] = dv * dinv[s[j]];
#pragma unroll
    for (int j = 0; j < 4; ++j) r[j] = hbf[(long)s[j] * CW + lane];
#pragma unroll
    for (int j = 0; j < 4; ++j) {
      a0 += nn[j] * bf2f((unsigned short)r[j]);
      a1 += nn[j] * bf2f((unsigned short)(r[j] >> 16));
    }
  }
  for (; e < re; ++e) {
    const int s0 = csr_src[e];
    const float n0 = dv * dinv[s0];
    const unsigned int r0 = hbf[(long)s0 * CW + lane];
    a0 += n0 * bf2f((unsigned short)r0);
    a1 += n0 * bf2f((unsigned short)(r0 >> 16));
  }

  const float s2 = dv * dv;
  const unsigned int hv = hbf[(long)v * CW + lane];
  float o0 = s2 * bf2f((unsigned short)hv) + a0;
  float o1 = s2 * bf2f((unsigned short)(hv >> 16)) + a1;
  if (HAS_BIAS) {
    const float2 bv = *(const float2*)(bias + lane * 2);
    o0 += bv.x;
    o1 += bv.y;
  }
  if (OUT_BF) {
    outBF[(long)v * CW + lane] = packBF2(o0, o1);
  } else {
    const float2 o = {o0, o1};
    *(float2*)(out + (long)v * CW * 2 + lane * 2) = o;
  }
}

// ---------------------------------------------------------------------------
extern "C" void kernel_launch(void* const* d_in, const int* in_sizes, int n_in,
                              void* d_out, int out_size, void* d_ws, size_t ws_size,
                              hipStream_t stream) {
  (void)in_sizes; (void)n_in; (void)out_size; (void)ws_size;

  const float* x  = (const float*)d_in[0];
  const int*   ei = (const int*)d_in[1];
  const float* W1 = (const float*)d_in[2];
  const float* b1 = (const float*)d_in[3];
  const float* W2 = (const float*)d_in[4];
  const float* b2 = (const float*)d_in[5];
  float* out = (float*)d_out;

  // Workspace layout (bytes):
  char* ws = (char*)d_ws;
  unsigned int* edata = (unsigned int*)(ws + 0);          //  3.2 MB (d | s<<16)
  int*   csr_src  = (int*)(ws + 3200000);      //  3.2 MB
  int*   H        = (int*)(ws + 6400000);      //  6.4 MB (8 x 32 x 6250)
  int*   rowstart = (int*)(ws + 12800000);     //  0.2 MB (N+1)
  float* dinv     = (float*)(ws + 13000512);   //  0.2 MB
  int*   bsum     = (int*)(ws + 13200512);
  int*   boff     = (int*)(ws + 13201536);
  unsigned int* w1bf   = (unsigned int*)(ws + 13300000);  // 65.5 KB
  unsigned int* w2bf   = (unsigned int*)(ws + 13400000);  // 65.5 KB
  unsigned int* aggxbf = (unsigned int*)(ws + 14000000);  // 12.8 MB (bf16 packed)
  unsigned int* h2bf   = (unsigned int*)(ws + 27000000);  // 12.8 MB (bf16 packed)
  unsigned int* xbf    = (unsigned int*)(ws + 91200000);  // 12.8 MB

  const int GB = (N_NODES + 3) / 4;  // gather: 1 node/wave

  // ---- Preproc: zero-atomic CSR build (stream, filter-hist, scan, scatter)
  convert_conv_k<<<EB + XCONV_BLKS + 2 * WCONV_BLKS, 256, 0, stream>>>(
      ei, edata, x, xbf, W1, w1bf, W2, w2bf);
  hist_k<<<NPART * KB2, 1024, 0, stream>>>(edata, H);
  bsum_k<<<NBLK, 256, 0, stream>>>(H, bsum);
  bscan_k<<<1, 256, 0, stream>>>(bsum, boff);
  bfinal_k<<<NBLK, 256, 0, stream>>>(H, boff, rowstart, dinv);
  scatter_k<<<NPART * KB2, 1024, 0, stream>>>(edata, H, csr_src);

  // ---- Layer 1 gather: aggx = agg(x_bf16) (bf16 out) ----
  gather_k<IN_C, false, true><<<GB, 256, 0, stream>>>(
      rowstart, csr_src, dinv, xbf, nullptr, nullptr, aggxbf);

  // ---- Fused GEMM1+GEMM2: h2 = relu(aggx@W1^T + b1) @ W2^T (h1 stays in LDS)
  gemm_fused_k<<<(N_NODES + 63) / 64, 256, 0, stream>>>(aggxbf, w1bf, b1, w2bf,
                                                        h2bf);

  // ---- Layer 2 gather: out = agg(h2_bf16) + b2 ----
  gather_k<OUT_C, true, false><<<GB, 256, 0, stream>>>(
      rowstart, csr_src, dinv, h2bf, b2, out, nullptr);
}

// Round 29
// 148.706 us; speedup vs baseline: 1.1293x; 1.0298x over previous
//
#include <hip/hip_runtime.h>

#define N_NODES 50000
#define N_EDGES 800000
#define IN_C 128
#define HID_C 256
#define OUT_C 128
#define NBLK 196   // ceil(N_NODES / 256)
#define NPART 8    // dst partitions (= XCDs); width 6250
#define PART_W 6250
#define KB2 32     // chunks per partition pass
#define CHUNK (N_EDGES / KB2)  // 25000 edges
#define EB 3125    // edge blocks (convert)
// scatter+conv merged kernel (1024 threads):
#define SC_SCAT 256                  // scatter blocks
#define SC_XC 1563                   // ceil(1600000 / 1024) x-float4 blocks

typedef __attribute__((ext_vector_type(8))) short short8v;  // 8 bf16
typedef __attribute__((ext_vector_type(4))) float f32x4;

static __device__ __forceinline__ unsigned short f2bf(float f) {
  unsigned int u = __float_as_uint(f);
  unsigned int r = (u + 0x7fffu + ((u >> 16) & 1u)) >> 16;  // RNE
  return (unsigned short)r;
}
static __device__ __forceinline__ float bf2f(unsigned short h) {
  return __uint_as_float(((unsigned int)h) << 16);
}
static __device__ __forceinline__ unsigned int packBF2(float a, float b) {
  return (unsigned int)f2bf(a) | ((unsigned int)f2bf(b) << 16);
}

// ---------------------------------------------------------------------------
// Edge conversion (streaming, no atomics): edata[e] = d | s<<16.
// Blocks [EB, EB+128): W1/W2 -> bf16 pairs (no dinv dependency).
// ---------------------------------------------------------------------------
__global__ __launch_bounds__(256) void convert_k(const int* __restrict__ ei,
                                                 unsigned int* __restrict__ edata,
                                                 const float* __restrict__ W1,
                                                 unsigned int* __restrict__ w1bf,
                                                 const float* __restrict__ W2,
                                                 unsigned int* __restrict__ w2bf) {
  const int b = blockIdx.x;
  if (b < EB) {
    __shared__ int s_is64;
    if (threadIdx.x == 0) {
      int nz = 0;
#pragma unroll
      for (int k = 0; k < 64; ++k) nz |= ei[2 * k + 1];
      s_is64 = (nz == 0) ? 1 : 0;
    }
    __syncthreads();
    const int is64 = s_is64;
    const int e = b * 256 + threadIdx.x;
    if (e < N_EDGES) {
      int s, d;
      if (is64) {
        const uint2 sv = ((const uint2*)ei)[e];            // low word = src
        const uint2 dv = ((const uint2*)ei)[N_EDGES + e];  // low word = dst
        s = (int)sv.x;
        d = (int)dv.x;
      } else {
        s = ei[e];
        d = ei[N_EDGES + e];
      }
      edata[e] = (unsigned int)d | ((unsigned int)s << 16);
    }
  } else if (b < EB + 64) {
    const int i = (b - EB) * 256 + threadIdx.x;  // u32 index
    const float2 f = *(const float2*)(W1 + (long)i * 2);
    w1bf[i] = packBF2(f.x, f.y);
  } else {
    const int i = (b - EB - 64) * 256 + threadIdx.x;
    const float2 f = *(const float2*)(W2 + (long)i * 2);
    w2bf[i] = packBF2(f.x, f.y);
  }
}

// ---------------------------------------------------------------------------
// Per-(partition,chunk) LDS histogram (zero global atomics).
// ---------------------------------------------------------------------------
__global__ __launch_bounds__(1024) void hist_k(const unsigned int* __restrict__ edata,
                                               int* __restrict__ H) {
  const int p = blockIdx.x & 7;
  const int c = blockIdx.x >> 3;
  __shared__ unsigned int hist[PART_W];
  for (int i = threadIdx.x; i < PART_W; i += 1024) hist[i] = 0;
  __syncthreads();
  const int s0 = c * CHUNK;
  for (int i = s0 + threadIdx.x; i < s0 + CHUNK; i += 1024) {
    const unsigned int u = edata[i];
    const int d = (int)(u & 0xffffu);
    if (d / PART_W == p) atomicAdd(&hist[d - p * PART_W], 1u);
  }
  __syncthreads();
  int* Hrow = H + (p * KB2 + c) * PART_W;
  for (int i = threadIdx.x; i < PART_W; i += 1024) Hrow[i] = (int)hist[i];
}

// ---------------------------------------------------------------------------
// Scans over H; bfinal emits rowstart, dinv, and per-(chunk,bin) bases.
// ---------------------------------------------------------------------------
__global__ __launch_bounds__(256) void bsum_k(const int* __restrict__ H,
                                              int* __restrict__ bsum) {
  const int i = blockIdx.x * 256 + threadIdx.x;
  int v = 0;
  if (i < N_NODES) {
    const int p = i / PART_W, bin = i % PART_W;
    const int* Hp = H + p * KB2 * PART_W + bin;
#pragma unroll
    for (int c = 0; c < KB2; ++c) v += Hp[c * PART_W];
  }
#pragma unroll
  for (int off = 32; off > 0; off >>= 1) v += __shfl_down(v, off, 64);
  __shared__ int ws[4];
  if ((threadIdx.x & 63) == 0) ws[threadIdx.x >> 6] = v;
  __syncthreads();
  if (threadIdx.x == 0) bsum[blockIdx.x] = ws[0] + ws[1] + ws[2] + ws[3];
}

__global__ __launch_bounds__(256) void bscan_k(const int* __restrict__ bsum,
                                               int* __restrict__ boff) {
  __shared__ int s[256];
  const int t = threadIdx.x;
  const int v = (t < NBLK) ? bsum[t] : 0;
  s[t] = v;
  __syncthreads();
  for (int off = 1; off < 256; off <<= 1) {
    const int tmp = (t >= off) ? s[t - off] : 0;
    __syncthreads();
    s[t] += tmp;
    __syncthreads();
  }
  if (t < NBLK) boff[t] = s[t] - v;
}

__global__ __launch_bounds__(256) void bfinal_k(int* __restrict__ H,
                                                const int* __restrict__ boff,
                                                int* __restrict__ rowstart,
                                                float* __restrict__ dinv) {
  __shared__ int s[256];
  const int t = threadIdx.x;
  const int i = blockIdx.x * 256 + t;
  int dtot = 0;
  int p = 0, bin = 0;
  if (i < N_NODES) {
    p = i / PART_W;
    bin = i % PART_W;
    int* Hp = H + p * KB2 * PART_W + bin;
#pragma unroll
    for (int c = 0; c < KB2; ++c) dtot += Hp[c * PART_W];
  }
  s[t] = dtot;
  __syncthreads();
  for (int off = 1; off < 256; off <<= 1) {
    const int tmp = (t >= off) ? s[t - off] : 0;
    __syncthreads();
    s[t] += tmp;
    __syncthreads();
  }
  const int run = boff[blockIdx.x] + s[t] - dtot;
  if (i < N_NODES) {
    rowstart[i] = run;
    dinv[i] = rsqrtf((float)dtot + 1.0f);
    int acc = run;
    int* Hp = H + p * KB2 * PART_W + bin;
#pragma unroll
    for (int c = 0; c < KB2; ++c) {
      const int cnt = Hp[c * PART_W];
      Hp[c * PART_W] = acc;
      acc += cnt;
    }
    if (i == N_NODES - 1) rowstart[N_NODES] = run + dtot;
  }
}

// ---------------------------------------------------------------------------
// MERGED scatter + dinv-scaled x conversion (needs dinv; runs after bfinal).
// Blocks [0,256): CSR scatter (p=bx&7, per-XCD dst-ranges).
// Blocks [256, 256+SC_XC): xbf[v][c] = bf16(dinv[v]*x[v][c]) (float4-wise).
// ---------------------------------------------------------------------------
__global__ __launch_bounds__(1024) void scatter_xconv_k(
    const unsigned int* __restrict__ edata, const int* __restrict__ H,
    int* __restrict__ csr_src, const float* __restrict__ x,
    const float* __restrict__ dinv, unsigned int* __restrict__ xbf) {
  const int b = blockIdx.x;
  if (b < SC_SCAT) {
    const int p = b & 7;
    const int c = b >> 3;
    __shared__ unsigned int hist[PART_W];
    for (int i = threadIdx.x; i < PART_W; i += 1024) hist[i] = 0;
    __syncthreads();
    const int s0 = c * CHUNK;
    const int* Hrow = H + (p * KB2 + c) * PART_W;
    for (int i = s0 + threadIdx.x; i < s0 + CHUNK; i += 1024) {
      const unsigned int u = edata[i];
      const int d = (int)(u & 0xffffu);
      if (d / PART_W == p) {
        const int ld = d - p * PART_W;
        const int lr = (int)atomicAdd(&hist[ld], 1u);
        csr_src[Hrow[ld] + lr] = (int)(u >> 16);
      }
    }
  } else {
    const int i = (b - SC_SCAT) * 1024 + threadIdx.x;  // float4 index
    if (i < N_NODES * IN_C / 4) {
      const int v = i >> 5;  // 32 float4 per 128-ch row
      const float dv = dinv[v];
      const float4 f = *(const float4*)(x + (long)i * 4);
      uint2 u = {packBF2(dv * f.x, dv * f.y), packBF2(dv * f.z, dv * f.w)};
      *(uint2*)(xbf + (long)i * 2) = u;
    }
  }
}

// ---------------------------------------------------------------------------
// FUSED both-layer GEMM, NT=64, W bf16. GEMM2 epilogue pre-scales h2 rows by
// dinv[n] (so gather2's per-edge term is a pure add).
// ---------------------------------------------------------------------------
__global__ __launch_bounds__(256) void gemm_fused_k(
    const unsigned int* __restrict__ X,     // aggx bf16-packed [N][64]
    const unsigned int* __restrict__ W1BF,  // [256][64] bf16-pairs
    const float* __restrict__ b1,
    const unsigned int* __restrict__ W2BF,  // [128][128] bf16-pairs
    const float* __restrict__ dinv,
    unsigned int* __restrict__ outBF) {     // dinv-scaled h2 bf16 [N][64]
  constexpr int KP1 = 68;   // aggx LDS row stride (64 + 4 pad)
  constexpr int HP = 132;   // h1 LDS row stride (128 + 4 pad)
  __shared__ unsigned int xs[64 * KP1];   // 17.4 KB
  __shared__ unsigned int h1s[64 * HP];   // 33.8 KB

  const int tid = threadIdx.x;
  const int w = tid >> 6;
  const int l = tid & 63;
  const long nbase = (long)blockIdx.x * 64;
  const int kg = (l >> 4) * 8;
  const int lr = l & 15;
  const int mq0 = (l >> 4) * 4;

  // ---- Stage aggx tile ----
#pragma unroll
  for (int i = 0; i < 4; ++i) {
    const int idx = (tid + i * 256) * 4;
    const int row = idx >> 6, col = idx & 63;
    long gr = nbase + row;
    if (gr > N_NODES - 1) gr = N_NODES - 1;
    const uint4 v = *(const uint4*)(X + gr * 64 + col);
    *(uint4*)(xs + row * KP1 + col) = v;
  }
  __syncthreads();

  // ---- GEMM1: wave w owns m in [w*64, w*64+64), K=128 ----
  {
    const int m0w = w * 64;
    f32x4 acc[4][4];
#pragma unroll
    for (int nt = 0; nt < 4; ++nt)
#pragma unroll
      for (int mt = 0; mt < 4; ++mt) acc[nt][mt] = {0.0f, 0.0f, 0.0f, 0.0f};

#pragma unroll
    for (int ks = 0; ks < 4; ++ks) {
      const int ko = ks * 32 + kg;
      short8v wb[4];
#pragma unroll
      for (int mt = 0; mt < 4; ++mt)
        wb[mt] = *(const short8v*)(W1BF + (long)(m0w + mt * 16 + lr) * (IN_C / 2) +
                                   ko / 2);
#pragma unroll
      for (int nt = 0; nt < 4; ++nt) {
        const short8v xb = *(const short8v*)(xs + (nt * 16 + lr) * KP1 + ko / 2);
#pragma unroll
        for (int mt = 0; mt < 4; ++mt)
          acc[nt][mt] = __builtin_amdgcn_mfma_f32_16x16x32_bf16(wb[mt], xb,
                                                               acc[nt][mt], 0, 0, 0);
      }
    }

#pragma unroll
    for (int nt = 0; nt < 4; ++nt) {
      const int nl = nt * 16 + lr;
#pragma unroll
      for (int mt = 0; mt < 4; ++mt) {
        const int mq = m0w + mt * 16 + mq0;
        const float4 bv = *(const float4*)(b1 + mq);
        const float v0 = fmaxf(acc[nt][mt][0] + bv.x, 0.0f);
        const float v1 = fmaxf(acc[nt][mt][1] + bv.y, 0.0f);
        const float v2 = fmaxf(acc[nt][mt][2] + bv.z, 0.0f);
        const float v3 = fmaxf(acc[nt][mt][3] + bv.w, 0.0f);
        uint2 o = {packBF2(v0, v1), packBF2(v2, v3)};
        *(uint2*)(h1s + nl * HP + mq / 2) = o;
      }
    }
  }
  __syncthreads();

  // ---- GEMM2: wave w owns m in [w*32, w*32+32), K=256 from LDS h1s ----
  {
    const int m0w = w * 32;
    f32x4 acc[4][2];
#pragma unroll
    for (int nt = 0; nt < 4; ++nt)
#pragma unroll
      for (int mt = 0; mt < 2; ++mt) acc[nt][mt] = {0.0f, 0.0f, 0.0f, 0.0f};

#pragma unroll
    for (int ks = 0; ks < 8; ++ks) {
      const int ko = ks * 32 + kg;
      short8v wb[2];
#pragma unroll
      for (int mt = 0; mt < 2; ++mt)
        wb[mt] = *(const short8v*)(W2BF + (long)(m0w + mt * 16 + lr) * (HID_C / 2) +
                                   ko / 2);
#pragma unroll
      for (int nt = 0; nt < 4; ++nt) {
        const short8v xb = *(const short8v*)(h1s + (nt * 16 + lr) * HP + ko / 2);
#pragma unroll
        for (int mt = 0; mt < 2; ++mt)
          acc[nt][mt] = __builtin_amdgcn_mfma_f32_16x16x32_bf16(wb[mt], xb,
                                                               acc[nt][mt], 0, 0, 0);
      }
    }

    // Epilogue 2: dinv[n]-scaled packed bf16 h2 to global
#pragma unroll
    for (int nt = 0; nt < 4; ++nt) {
      const long n = nbase + nt * 16 + lr;
      if (n < N_NODES) {
        const float dvn = dinv[n];
#pragma unroll
        for (int mt = 0; mt < 2; ++mt) {
          const int mq = m0w + mt * 16 + mq0;
          uint2 o = {packBF2(dvn * acc[nt][mt][0], dvn * acc[nt][mt][1]),
                     packBF2(dvn * acc[nt][mt][2], dvn * acc[nt][mt][3])};
          *(uint2*)(outBF + n * (OUT_C / 2) + mq / 2) = o;
        }
      }
    }
  }
}

// ---------------------------------------------------------------------------
// Gather over PRE-SCALED bf16 rows: single dependent load per edge, pure-add
// accumulation; final out = dinv[v]*(acc + self) (+bias). 16/8/4/1 unroll.
// OUT_BF: pack bf16 (feeds GEMM1). Else fp32 final output.
// ---------------------------------------------------------------------------
template <int C, bool HAS_BIAS, bool OUT_BF>
__global__ __launch_bounds__(256) void gather_k(const int* __restrict__ rowstart,
                                                const int* __restrict__ csr_src,
                                                const float* __restrict__ dinv,
                                                const unsigned int* __restrict__ hbf,
                                                const float* __restrict__ bias,
                                                float* __restrict__ out,
                                                unsigned int* __restrict__ outBF) {
  const int v = (blockIdx.x * 256 + threadIdx.x) >> 6;
  if (v >= N_NODES) return;
  const int lane = threadIdx.x & 63;
  constexpr int CW = C / 2;
  const int rs = rowstart[v];
  const int re = rowstart[v + 1];
  const float dv = dinv[v];

  float a0 = 0.0f, a1 = 0.0f;

  int e = rs;
  for (; e + 15 < re; e += 16) {
    int s[16];
    unsigned int r[16];
#pragma unroll
    for (int j = 0; j < 16; ++j) s[j] = csr_src[e + j];
#pragma unroll
    for (int j = 0; j < 16; ++j) r[j] = hbf[(long)s[j] * CW + lane];
#pragma unroll
    for (int j = 0; j < 16; ++j) {
      a0 += bf2f((unsigned short)r[j]);
      a1 += bf2f((unsigned short)(r[j] >> 16));
    }
  }
  for (; e + 7 < re; e += 8) {
    int s[8];
    unsigned int r[8];
#pragma unroll
    for (int j = 0; j < 8; ++j) s[j] = csr_src[e + j];
#pragma unroll
    for (int j = 0; j < 8; ++j) r[j] = hbf[(long)s[j] * CW + lane];
#pragma unroll
    for (int j = 0; j < 8; ++j) {
      a0 += bf2f((unsigned short)r[j]);
      a1 += bf2f((unsigned short)(r[j] >> 16));
    }
  }
  for (; e + 3 < re; e += 4) {
    int s[4];
    unsigned int r[4];
#pragma unroll
    for (int j = 0; j < 4; ++j) s[j] = csr_src[e + j];
#pragma unroll
    for (int j = 0; j < 4; ++j) r[j] = hbf[(long)s[j] * CW + lane];
#pragma unroll
    for (int j = 0; j < 4; ++j) {
      a0 += bf2f((unsigned short)r[j]);
      a1 += bf2f((unsigned short)(r[j] >> 16));
    }
  }
  for (; e < re; ++e) {
    const unsigned int r0 = hbf[(long)csr_src[e] * CW + lane];
    a0 += bf2f((unsigned short)r0);
    a1 += bf2f((unsigned short)(r0 >> 16));
  }

  const unsigned int hv = hbf[(long)v * CW + lane];
  float o0 = dv * (a0 + bf2f((unsigned short)hv));
  float o1 = dv * (a1 + bf2f((unsigned short)(hv >> 16)));
  if (HAS_BIAS) {
    const float2 bv = *(const float2*)(bias + lane * 2);
    o0 += bv.x;
    o1 += bv.y;
  }
  if (OUT_BF) {
    outBF[(long)v * CW + lane] = packBF2(o0, o1);
  } else {
    const float2 o = {o0, o1};
    *(float2*)(out + (long)v * CW * 2 + lane * 2) = o;
  }
}

// ---------------------------------------------------------------------------
extern "C" void kernel_launch(void* const* d_in, const int* in_sizes, int n_in,
                              void* d_out, int out_size, void* d_ws, size_t ws_size,
                              hipStream_t stream) {
  (void)in_sizes; (void)n_in; (void)out_size; (void)ws_size;

  const float* x  = (const float*)d_in[0];
  const int*   ei = (const int*)d_in[1];
  const float* W1 = (const float*)d_in[2];
  const float* b1 = (const float*)d_in[3];
  const float* W2 = (const float*)d_in[4];
  const float* b2 = (const float*)d_in[5];
  float* out = (float*)d_out;

  // Workspace layout (bytes):
  char* ws = (char*)d_ws;
  unsigned int* edata = (unsigned int*)(ws + 0);          //  3.2 MB (d | s<<16)
  int*   csr_src  = (int*)(ws + 3200000);      //  3.2 MB
  int*   H        = (int*)(ws + 6400000);      //  6.4 MB (8 x 32 x 6250)
  int*   rowstart = (int*)(ws + 12800000);     //  0.2 MB (N+1)
  float* dinv     = (float*)(ws + 13000512);   //  0.2 MB
  int*   bsum     = (int*)(ws + 13200512);
  int*   boff     = (int*)(ws + 13201536);
  unsigned int* w1bf   = (unsigned int*)(ws + 13300000);  // 65.5 KB
  unsigned int* w2bf   = (unsigned int*)(ws + 13400000);  // 65.5 KB
  unsigned int* aggxbf = (unsigned int*)(ws + 14000000);  // 12.8 MB (bf16 packed)
  unsigned int* h2bf   = (unsigned int*)(ws + 27000000);  // 12.8 MB (dinv-scaled)
  unsigned int* xbf    = (unsigned int*)(ws + 91200000);  // 12.8 MB (dinv-scaled)

  const int GB = (N_NODES + 3) / 4;  // gather: 1 node/wave

  // ---- Preproc: zero-atomic CSR build; x-conv (dinv-scaled) after bfinal ----
  convert_k<<<EB + 128, 256, 0, stream>>>(ei, edata, W1, w1bf, W2, w2bf);
  hist_k<<<NPART * KB2, 1024, 0, stream>>>(edata, H);
  bsum_k<<<NBLK, 256, 0, stream>>>(H, bsum);
  bscan_k<<<1, 256, 0, stream>>>(bsum, boff);
  bfinal_k<<<NBLK, 256, 0, stream>>>(H, boff, rowstart, dinv);
  scatter_xconv_k<<<SC_SCAT + SC_XC, 1024, 0, stream>>>(edata, H, csr_src, x,
                                                        dinv, xbf);

  // ---- Layer 1 gather: aggx = dinv*(sum + self) over pre-scaled xbf ----
  gather_k<IN_C, false, true><<<GB, 256, 0, stream>>>(
      rowstart, csr_src, dinv, xbf, nullptr, nullptr, aggxbf);

  // ---- Fused GEMM1+GEMM2 (h2 pre-scaled by dinv in epilogue) ----
  gemm_fused_k<<<(N_NODES + 63) / 64, 256, 0, stream>>>(aggxbf, w1bf, b1, w2bf,
                                                        dinv, h2bf);

  // ---- Layer 2 gather: out = b2 + dinv*(sum + self) over pre-scaled h2 ----
  gather_k<OUT_C, true, false><<<GB, 256, 0, stream>>>(
      rowstart, csr_src, dinv, h2bf, b2, out, nullptr);
}